// Round 4
// baseline (75.838 us; speedup 1.0000x reference)
//
#include <hip/hip_runtime.h>

// loss = (N*S - ||colsum||^2) / (sqrt(max_i sq_i) * N*(N-1)/2)
// where S = sum of all x^2, colsum[d] = sum_i x[i][d], sq_i = row squared norm.
// Derivation: sum_{i<j} (sq_i + sq_j - 2 x_i.x_j) = N*S - ||colsum||^2.
//
// 3-stage, no global atomics:
//   pass1  (512 blocks x 512 thr, 16 waves/CU): per-block colsum[512]/S/max
//          partials, plain stores (no init -> no memset dispatch).
//   pass2a ( 64 blocks): block j reduces cols [8j,8j+8) over the 512
//          block-partials -> sum-of-squares partial; plus 8-wide S/max slice.
//   pass2b (  1 block ): reduces 64+64+64 floats, emits the scalar.

#define NROWS 8192
#define NCOLS 512
#define NB1   512                 // pass1 block count
#define NT1   512                 // pass1 threads/block (8 waves)
#define NB2   64                  // pass2a block count
#define PS    (NB1 * NCOLS)       // ws: S partials [NB1]
#define PM    (PS + NB1)          // ws: max partials [NB1]
#define PQ    (PM + NB1)          // ws: ssq stage-2 partials [NB2]
#define PS2   (PQ + NB2)          // ws: S stage-2 [NB2]
#define PM2   (PS2 + NB2)         // ws: max stage-2 [NB2]

__global__ __launch_bounds__(NT1) void ndl_pass1(const float* __restrict__ x,
                                                 float* __restrict__ ws) {
    __shared__ float colsum[NCOLS];
    __shared__ float s_part[8];
    __shared__ float m_part[8];
    const int t    = threadIdx.x;
    const int lane = t & 63;
    const int wave = t >> 6;

    colsum[t] = 0.f;
    __syncthreads();

    // wave handles 2 consecutive rows; lane l covers columns 8l..8l+7
    const int row0 = blockIdx.x * 16 + wave * 2;
    const float4* xv = (const float4*)x;  // row stride = 128 float4

    float col[8] = {0.f, 0.f, 0.f, 0.f, 0.f, 0.f, 0.f, 0.f};
    float sp = 0.f;
    float maxsq = 0.f;

    #pragma unroll
    for (int r = 0; r < 2; ++r) {
        const int row = row0 + r;
        float4 a = xv[row * 128 + lane * 2];
        float4 b = xv[row * 128 + lane * 2 + 1];
        col[0] += a.x; col[1] += a.y; col[2] += a.z; col[3] += a.w;
        col[4] += b.x; col[5] += b.y; col[6] += b.z; col[7] += b.w;
        float rsq = a.x*a.x + a.y*a.y + a.z*a.z + a.w*a.w
                  + b.x*b.x + b.y*b.y + b.z*b.z + b.w*b.w;
        sp += rsq;
        // butterfly: all lanes end with the full row sq
        #pragma unroll
        for (int off = 1; off < 64; off <<= 1)
            rsq += __shfl_xor(rsq, off, 64);
        maxsq = fmaxf(maxsq, rsq);
    }

    // per-lane column partials -> LDS (8-way wave contention, LDS atomics)
    const int base = lane * 8;
    #pragma unroll
    for (int k = 0; k < 8; ++k)
        atomicAdd(&colsum[base + k], col[k]);

    #pragma unroll
    for (int off = 1; off < 64; off <<= 1)
        sp += __shfl_xor(sp, off, 64);
    if (lane == 0) { s_part[wave] = sp; m_part[wave] = maxsq; }
    __syncthreads();

    // plain stores of per-block partials — no global atomics, no pre-zero
    float* o = ws + (size_t)blockIdx.x * NCOLS;
    o[t] = colsum[t];
    if (t == 0) {
        float s = 0.f, m = 0.f;
        #pragma unroll
        for (int w = 0; w < 8; ++w) {
            s += s_part[w];
            m  = fmaxf(m, m_part[w]);
        }
        ws[PS + blockIdx.x] = s;
        ws[PM + blockIdx.x] = m;
    }
}

// Block j: columns c = 8j..8j+7, fully summed over all 512 pass1 blocks.
// Thread t: c' = t&7, i = t>>3 (0..31); sums sets b = i*16+k, k=0..15.
__global__ __launch_bounds__(256) void ndl_pass2a(const float* __restrict__ ws_in,
                                                  float* __restrict__ ws) {
    __shared__ float wred[4 * 8];   // [wave][col'] per-wave column partials
    const int t    = threadIdx.x;
    const int lane = t & 63;
    const int wave = t >> 6;
    const int j    = blockIdx.x;
    const int c    = j * 8 + (t & 7);
    const int i    = t >> 3;

    const float* p = ws_in + (size_t)(i * 16) * NCOLS + c;
    float acc = 0.f;
    #pragma unroll
    for (int k = 0; k < 16; ++k)
        acc += p[(size_t)k * NCOLS];

    // sum over the 8 i-values within this wave (t bits 3,4,5)
    acc += __shfl_xor(acc, 8, 64);
    acc += __shfl_xor(acc, 16, 64);
    acc += __shfl_xor(acc, 32, 64);
    if (lane < 8) wred[wave * 8 + lane] = acc;
    __syncthreads();

    if (t < 8) {
        float cs = wred[t] + wred[8 + t] + wred[16 + t] + wred[24 + t];
        float q  = cs * cs;
        q += __shfl_xor(q, 1, 64);
        q += __shfl_xor(q, 2, 64);
        q += __shfl_xor(q, 4, 64);
        if (t == 0) ws[PQ + j] = q;
    }
    if (t == 0) {
        float s = 0.f, m = 0.f;
        #pragma unroll
        for (int k = 0; k < 8; ++k) {
            s += ws_in[PS + j * 8 + k];
            m  = fmaxf(m, ws_in[PM + j * 8 + k]);
        }
        ws[PS2 + j] = s;
        ws[PM2 + j] = m;
    }
}

__global__ __launch_bounds__(64) void ndl_pass2b(const float* __restrict__ ws,
                                                 float* __restrict__ out) {
    const int t = threadIdx.x;
    float qv = ws[PQ + t];
    float sv = ws[PS2 + t];
    float mv = ws[PM2 + t];
    #pragma unroll
    for (int off = 1; off < 64; off <<= 1) {
        qv += __shfl_xor(qv, off, 64);
        sv += __shfl_xor(sv, off, 64);
        mv  = fmaxf(mv, __shfl_xor(mv, off, 64));
    }
    if (t == 0) {
        double numer = (double)NROWS * (double)sv - (double)qv;
        double count = (double)NROWS * ((double)NROWS - 1.0) * 0.5;
        out[0] = (float)(numer / (sqrt((double)mv) * count));
    }
}

extern "C" void kernel_launch(void* const* d_in, const int* in_sizes, int n_in,
                              void* d_out, int out_size, void* d_ws, size_t ws_size,
                              hipStream_t stream) {
    const float* x = (const float*)d_in[0];
    float* out = (float*)d_out;
    float* ws  = (float*)d_ws;

    ndl_pass1<<<NB1, NT1, 0, stream>>>(x, ws);
    ndl_pass2a<<<NB2, 256, 0, stream>>>(ws, ws);
    ndl_pass2b<<<1, 64, 0, stream>>>(ws, out);
}

// Round 5
// 70.122 us; speedup vs baseline: 1.0815x; 1.0815x over previous
//
#include <hip/hip_runtime.h>

// loss = (N*S - ||colsum||^2) / (sqrt(max_i sq_i) * N*(N-1)/2)
// where S = sum of all x^2, colsum[d] = sum_i x[i][d], sq_i = row squared norm.
// Derivation: sum_{i<j} (sq_i + sq_j - 2 x_i.x_j) = N*S - ||colsum||^2.
//
// 2-stage, no global atomics on data (one counter atomic only):
//   pass1 (256 blocks x 256 thr): per-block colsum[512]/S/max partials,
//         plain stores (no init -> no memset dispatch). 8 rows/wave = 16
//         float4 loads of ILP per lane (proven round-3 shape; 512-thread
//         variant regressed: ILP 16->4 + 2x LDS-atomic contention).
//   pass2 ( 64 blocks): block j reduces cols [8j,8j+8) over the 256
//         block-partials -> ssq partial + S/max slice; LAST block (counter)
//         reduces the 64 stage-2 partials and emits the scalar.

#define NROWS 8192
#define NCOLS 512
#define NB1   256                 // pass1 block count
#define NB2   64                  // pass2 block count
#define PS    (NB1 * NCOLS)       // ws: S partials [NB1]
#define PM    (PS + NB1)          // ws: max partials [NB1]
#define PQ    (PM + NB1)          // ws: ssq stage-2 partials [NB2]
#define PS2   (PQ + NB2)          // ws: S stage-2 [NB2]
#define PM2   (PS2 + NB2)         // ws: max stage-2 [NB2]
#define PCNT  (PM2 + NB2)         // ws: completion counter (int), pass1 zeroes

__global__ __launch_bounds__(256) void ndl_pass1(const float* __restrict__ x,
                                                 float* __restrict__ ws) {
    __shared__ float colsum[NCOLS];
    __shared__ float s_part[4];
    __shared__ float m_part[4];
    const int t    = threadIdx.x;
    const int lane = t & 63;
    const int wave = t >> 6;

    colsum[t]       = 0.f;
    colsum[t + 256] = 0.f;
    __syncthreads();

    // wave handles 8 consecutive rows; lane l covers columns 8l..8l+7
    const int row0 = blockIdx.x * 32 + wave * 8;
    const float4* xv = (const float4*)x;  // row stride = 128 float4

    float col[8] = {0.f, 0.f, 0.f, 0.f, 0.f, 0.f, 0.f, 0.f};
    float sp = 0.f;
    float maxsq = 0.f;

    #pragma unroll
    for (int r = 0; r < 8; ++r) {
        const int row = row0 + r;
        float4 a = xv[row * 128 + lane * 2];
        float4 b = xv[row * 128 + lane * 2 + 1];
        col[0] += a.x; col[1] += a.y; col[2] += a.z; col[3] += a.w;
        col[4] += b.x; col[5] += b.y; col[6] += b.z; col[7] += b.w;
        float rsq = a.x*a.x + a.y*a.y + a.z*a.z + a.w*a.w
                  + b.x*b.x + b.y*b.y + b.z*b.z + b.w*b.w;
        sp += rsq;
        // butterfly: all lanes end with the full row sq
        #pragma unroll
        for (int off = 1; off < 64; off <<= 1)
            rsq += __shfl_xor(rsq, off, 64);
        maxsq = fmaxf(maxsq, rsq);
    }

    // per-lane column partials -> LDS (4-way wave contention, LDS atomics)
    const int base = lane * 8;
    #pragma unroll
    for (int k = 0; k < 8; ++k)
        atomicAdd(&colsum[base + k], col[k]);

    #pragma unroll
    for (int off = 1; off < 64; off <<= 1)
        sp += __shfl_xor(sp, off, 64);
    if (lane == 0) { s_part[wave] = sp; m_part[wave] = maxsq; }
    __syncthreads();

    // plain stores of per-block partials — no global atomics, no pre-zero
    float* o = ws + (size_t)blockIdx.x * NCOLS;
    o[t]       = colsum[t];
    o[t + 256] = colsum[t + 256];
    if (t == 0) {
        ws[PS + blockIdx.x] = s_part[0] + s_part[1] + s_part[2] + s_part[3];
        ws[PM + blockIdx.x] = fmaxf(fmaxf(m_part[0], m_part[1]),
                                    fmaxf(m_part[2], m_part[3]));
        if (blockIdx.x == 0)
            *(int*)(ws + PCNT) = 0;   // visible to pass2 via kernel-end flush
    }
}

// Block j: columns c = 8j..8j+7, fully summed over all 256 pass1 blocks.
// Thread t: c' = t&7, i = t>>3 (0..31); sums sets b = i*8+k, k=0..7.
// The last block to finish also performs the final 64-wide reduction.
__global__ __launch_bounds__(256) void ndl_pass2(const float* __restrict__ ws_in,
                                                 float* __restrict__ ws,
                                                 float* __restrict__ out) {
    __shared__ float wred[4 * 8];   // [wave][col'] per-wave column partials
    __shared__ int   is_last;
    const int t    = threadIdx.x;
    const int lane = t & 63;
    const int wave = t >> 6;
    const int j    = blockIdx.x;
    const int c    = j * 8 + (t & 7);
    const int i    = t >> 3;

    const float* p = ws_in + (size_t)(i * 8) * NCOLS + c;
    float acc = 0.f;
    #pragma unroll
    for (int k = 0; k < 8; ++k)
        acc += p[(size_t)k * NCOLS];

    // sum over the 8 i-values within this wave (lane bits 3,4,5)
    acc += __shfl_xor(acc, 8, 64);
    acc += __shfl_xor(acc, 16, 64);
    acc += __shfl_xor(acc, 32, 64);
    if (lane < 8) wred[wave * 8 + lane] = acc;
    __syncthreads();

    if (t < 8) {
        float cs = wred[t] + wred[8 + t] + wred[16 + t] + wred[24 + t];
        float q  = cs * cs;
        q += __shfl_xor(q, 1, 64);
        q += __shfl_xor(q, 2, 64);
        q += __shfl_xor(q, 4, 64);
        if (t == 0) ws[PQ + j] = q;
    }
    if (t == 0) {
        float s = 0.f, m = 0.f;
        #pragma unroll
        for (int k = 0; k < 4; ++k) {
            s += ws_in[PS + j * 4 + k];
            m  = fmaxf(m, ws_in[PM + j * 4 + k]);
        }
        ws[PS2 + j] = s;
        ws[PM2 + j] = m;
        __threadfence();                       // release our partials
        int old = atomicAdd((int*)(ws + PCNT), 1);
        is_last = (old == NB2 - 1) ? 1 : 0;
    }
    __syncthreads();

    if (is_last) {
        __threadfence();                       // acquire others' partials
        if (t < 64) {
            float qv = ws[PQ + t];
            float sv = ws[PS2 + t];
            float mv = ws[PM2 + t];
            #pragma unroll
            for (int off = 1; off < 64; off <<= 1) {
                qv += __shfl_xor(qv, off, 64);
                sv += __shfl_xor(sv, off, 64);
                mv  = fmaxf(mv, __shfl_xor(mv, off, 64));
            }
            if (t == 0) {
                double numer = (double)NROWS * (double)sv - (double)qv;
                double count = (double)NROWS * ((double)NROWS - 1.0) * 0.5;
                out[0] = (float)(numer / (sqrt((double)mv) * count));
            }
        }
    }
}

extern "C" void kernel_launch(void* const* d_in, const int* in_sizes, int n_in,
                              void* d_out, int out_size, void* d_ws, size_t ws_size,
                              hipStream_t stream) {
    const float* x = (const float*)d_in[0];
    float* out = (float*)d_out;
    float* ws  = (float*)d_ws;

    ndl_pass1<<<NB1, 256, 0, stream>>>(x, ws);
    ndl_pass2<<<NB2, 256, 0, stream>>>(ws, ws, out);
}